// Round 1
// baseline (47759.619 us; speedup 1.0000x reference)
//
#include <hip/hip_runtime.h>
#include <hip/hip_bf16.h>

// Problem dims (fixed by reference): N=256, T=32, F=H=512, L=2
#define HD 512
#define TT 32
#define NB 256
#define SEQROWS 8193          // 1 zero row + up to 8192 chain steps
#define GA 32                 // workgroups per role (A=layer0, B=layer1)

__device__ __forceinline__ float fast_sigmoid(float x) {
    return 1.0f / (1.0f + __expf(-x));
}
__device__ __forceinline__ float fast_tanh(float x) {
    return 1.0f - 2.0f / (__expf(2.0f * x) + 1.0f);
}

__device__ __forceinline__ void wait_cnt(int* p) {
    // relaxed agent-scope poll; acquire fence performed by caller after success
    int it = 0;
    while (__hip_atomic_load(p, __ATOMIC_RELAXED, __HIP_MEMORY_SCOPE_AGENT) < GA) {
        __builtin_amdgcn_s_sleep(1);
        if (++it > 20000000) break;   // bailout: fail loudly rather than hang
    }
}

// ---------------------------------------------------------------------------
// init: block 0 -> scan dates, build active list / output map, zero h rows,
//       write dates to out; blocks 1..64 -> zero the 16384 step counters.
// ---------------------------------------------------------------------------
__global__ __launch_bounds__(256) void init_kernel(
    const int* __restrict__ dates, float* __restrict__ out,
    float* __restrict__ h0seq, float* __restrict__ h1seq,
    int* __restrict__ cnt, int* __restrict__ act_idx,
    int* __restrict__ jmap, int* __restrict__ S_ptr)
{
    const int b = blockIdx.x, tid = threadIdx.x;
    if (b == 0) {
        __shared__ int sc[NB];
        int d = dates[tid];
        int active = (tid == 0) ? 1 : (d != dates[tid - 1] ? 1 : 0);
        sc[tid] = active;
        for (int off = 1; off < NB; off <<= 1) {
            __syncthreads();
            int v = sc[tid] + ((tid >= off) ? sc[tid - off] : 0);
            __syncthreads();
            sc[tid] = v;
        }
        __syncthreads();
        int incl = sc[tid];               // inclusive count of actives in [0..tid]
        jmap[tid] = incl - 1;             // which active element's output this copies
        if (active) act_idx[incl - 1] = tid;
        if (tid == NB - 1) *S_ptr = incl * TT;
        out[tid] = (float)d;              // output 0: dates passthrough
        for (int i = tid; i < HD; i += 256) { h0seq[i] = 0.f; h1seq[i] = 0.f; }
    } else {
        cnt[(b - 1) * 256 + tid] = 0;     // 64*256 = 16384 = cntA(8192)+cntB(8192)
    }
}

// ---------------------------------------------------------------------------
// chain: 64 persistent WGs. WGs 0..31 = layer0 chain (input x), WGs 32..63 =
// layer1 chain (input = layer0's published h0). Weights register-resident:
// each WG owns 16 h-outputs; thread (hl,c) holds rows {r,z,n} x 16 cols of
// both Wih and Whh. 32-lane shuffle reduction -> gate math on lane c==0.
// ---------------------------------------------------------------------------
__global__ __launch_bounds__(512, 2) void chain_kernel(
    const float* __restrict__ x,
    const float* __restrict__ Wih0, const float* __restrict__ Whh0,
    const float* __restrict__ bih0, const float* __restrict__ bhh0,
    const float* __restrict__ Wih1, const float* __restrict__ Whh1,
    const float* __restrict__ bih1, const float* __restrict__ bhh1,
    float* __restrict__ h0seq, float* __restrict__ h1seq,
    int* cntA, int* cntB,
    const int* __restrict__ act_idx, const int* __restrict__ S_ptr)
{
    const int wg   = blockIdx.x;
    const bool roleB = (wg >= GA);
    const int g    = roleB ? wg - GA : wg;     // 0..31
    const int tid  = threadIdx.x;
    const int hl   = tid >> 5;                 // 0..15: local h index
    const int c    = tid & 31;                 // 0..31: column group
    const int hi   = g * 16 + hl;              // 0..511: owned h output
    const int col0 = c * 16;

    const float* Wi = roleB ? Wih1 : Wih0;
    const float* Wh = roleB ? Whh1 : Whh0;
    const float* bi = roleB ? bih1 : bih0;
    const float* bh = roleB ? bhh1 : bhh0;

    // ---- load this thread's 96 weights into registers ----
    float wir[16], wiz[16], win[16], whr[16], whz[16], whn[16];
    {
        const float* bI = Wi + (size_t)hi * HD + col0;   // row hi (r gate)
        const float* bH = Wh + (size_t)hi * HD + col0;
        const size_t GSTRIDE = (size_t)HD * HD;          // gate-to-gate row offset
#pragma unroll
        for (int q = 0; q < 4; q++) {
            float4 v;
            v = *reinterpret_cast<const float4*>(bI + 4 * q);
            wir[4*q]=v.x; wir[4*q+1]=v.y; wir[4*q+2]=v.z; wir[4*q+3]=v.w;
            v = *reinterpret_cast<const float4*>(bI + GSTRIDE + 4 * q);
            wiz[4*q]=v.x; wiz[4*q+1]=v.y; wiz[4*q+2]=v.z; wiz[4*q+3]=v.w;
            v = *reinterpret_cast<const float4*>(bI + 2*GSTRIDE + 4 * q);
            win[4*q]=v.x; win[4*q+1]=v.y; win[4*q+2]=v.z; win[4*q+3]=v.w;
            v = *reinterpret_cast<const float4*>(bH + 4 * q);
            whr[4*q]=v.x; whr[4*q+1]=v.y; whr[4*q+2]=v.z; whr[4*q+3]=v.w;
            v = *reinterpret_cast<const float4*>(bH + GSTRIDE + 4 * q);
            whz[4*q]=v.x; whz[4*q+1]=v.y; whz[4*q+2]=v.z; whz[4*q+3]=v.w;
            v = *reinterpret_cast<const float4*>(bH + 2*GSTRIDE + 4 * q);
            whn[4*q]=v.x; whn[4*q+1]=v.y; whn[4*q+2]=v.z; whn[4*q+3]=v.w;
        }
    }
    const float br   = bi[hi] + bh[hi];
    const float bz   = bi[HD + hi] + bh[HD + hi];
    const float bin_ = bi[2 * HD + hi];
    const float bhn_ = bh[2 * HD + hi];

    const int S = *S_ptr;
    float* outseq = roleB ? h1seq : h0seq;
    float hown = 0.0f;   // leader lanes carry their own h across all steps

    for (int s = 0; s < S; s++) {
        // ---- wait for dependencies ----
        if (tid == 0) {
            if (!roleB) {
                if (s > 0) wait_cnt(cntA + s - 1);          // full h0(prev) row
            } else {
                wait_cnt(cntA + s);                          // h0(s) from role A
                if (s > 0) wait_cnt(cntB + s - 1);           // own h1(prev) row
            }
        }
        __syncthreads();
        __builtin_amdgcn_fence(__ATOMIC_ACQUIRE, "agent");   // invalidate stale

        const float* invec;
        if (!roleB) {
            int n = act_idx[s >> 5];                          // active element
            invec = x + ((size_t)n * TT + (s & 31)) * HD;     // x[n, t, :]
        } else {
            invec = h0seq + (size_t)(s + 1) * HD;             // h0 after step s
        }
        const float* hvec = outseq + (size_t)s * HD;          // own h after s-1

        float pr = 0.f, pz = 0.f, pin = 0.f, phn = 0.f;
#pragma unroll
        for (int q = 0; q < 4; q++) {
            const float4 xv = *reinterpret_cast<const float4*>(invec + col0 + 4 * q);
            const float4 hv = *reinterpret_cast<const float4*>(hvec + col0 + 4 * q);
            pr  = fmaf(wir[4*q+0], xv.x, pr);  pr  = fmaf(wir[4*q+1], xv.y, pr);
            pr  = fmaf(wir[4*q+2], xv.z, pr);  pr  = fmaf(wir[4*q+3], xv.w, pr);
            pr  = fmaf(whr[4*q+0], hv.x, pr);  pr  = fmaf(whr[4*q+1], hv.y, pr);
            pr  = fmaf(whr[4*q+2], hv.z, pr);  pr  = fmaf(whr[4*q+3], hv.w, pr);
            pz  = fmaf(wiz[4*q+0], xv.x, pz);  pz  = fmaf(wiz[4*q+1], xv.y, pz);
            pz  = fmaf(wiz[4*q+2], xv.z, pz);  pz  = fmaf(wiz[4*q+3], xv.w, pz);
            pz  = fmaf(whz[4*q+0], hv.x, pz);  pz  = fmaf(whz[4*q+1], hv.y, pz);
            pz  = fmaf(whz[4*q+2], hv.z, pz);  pz  = fmaf(whz[4*q+3], hv.w, pz);
            pin = fmaf(win[4*q+0], xv.x, pin); pin = fmaf(win[4*q+1], xv.y, pin);
            pin = fmaf(win[4*q+2], xv.z, pin); pin = fmaf(win[4*q+3], xv.w, pin);
            phn = fmaf(whn[4*q+0], hv.x, phn); phn = fmaf(whn[4*q+1], hv.y, phn);
            phn = fmaf(whn[4*q+2], hv.z, phn); phn = fmaf(whn[4*q+3], hv.w, phn);
        }
        // ---- reduce across the 32 column-group lanes (stays within wave) ----
#pragma unroll
        for (int m = 1; m < 32; m <<= 1) {
            pr  += __shfl_xor(pr,  m, 64);
            pz  += __shfl_xor(pz,  m, 64);
            pin += __shfl_xor(pin, m, 64);
            phn += __shfl_xor(phn, m, 64);
        }
        if (c == 0) {
            float r  = fast_sigmoid(pr + br);
            float z  = fast_sigmoid(pz + bz);
            float nn = fast_tanh(pin + bin_ + r * (phn + bhn_));
            hown = (1.0f - z) * nn + z * hown;
            outseq[(size_t)(s + 1) * HD + hi] = hown;
        }
        __builtin_amdgcn_fence(__ATOMIC_RELEASE, "agent");   // drain stores
        __syncthreads();
        if (tid == 0) {
            __hip_atomic_fetch_add(roleB ? (cntB + s) : (cntA + s), 1,
                                   __ATOMIC_RELEASE, __HIP_MEMORY_SCOPE_AGENT);
        }
    }
}

// ---------------------------------------------------------------------------
// finalize: states[n] = h1 after last step of active element jmap[n]
// ---------------------------------------------------------------------------
__global__ __launch_bounds__(256) void finalize_kernel(
    const float* __restrict__ h1seq, const int* __restrict__ jmap,
    float* __restrict__ out)
{
    const int n = blockIdx.x;
    const int j = jmap[n];
    const float* src = h1seq + ((size_t)j * TT + TT) * HD;   // row j*32+32
    float* dst = out + NB + (size_t)n * HD;
    for (int i = threadIdx.x; i < HD; i += 256) dst[i] = src[i];
}

extern "C" void kernel_launch(void* const* d_in, const int* in_sizes, int n_in,
                              void* d_out, int out_size, void* d_ws, size_t ws_size,
                              hipStream_t stream)
{
    const int*   dates = (const int*)d_in[0];
    const float* x     = (const float*)d_in[1];
    const float* Wih0  = (const float*)d_in[2];
    const float* Whh0  = (const float*)d_in[3];
    const float* bih0  = (const float*)d_in[4];
    const float* bhh0  = (const float*)d_in[5];
    const float* Wih1  = (const float*)d_in[6];
    const float* Whh1  = (const float*)d_in[7];
    const float* bih1  = (const float*)d_in[8];
    const float* bhh1  = (const float*)d_in[9];
    float* out = (float*)d_out;

    // workspace layout (~33.7 MB)
    float* h0seq  = (float*)d_ws;                       // 8193*512
    float* h1seq  = h0seq + (size_t)SEQROWS * HD;       // 8193*512
    int*   cnt    = (int*)(h1seq + (size_t)SEQROWS * HD);
    int*   cntA   = cnt;                                // 8192
    int*   cntB   = cnt + 8192;                         // 8192
    int*   act_i  = cnt + 16384;                        // 256
    int*   jmap   = act_i + NB;                         // 256
    int*   S_ptr  = jmap + NB;                          // 1

    hipLaunchKernelGGL(init_kernel, dim3(65), dim3(256), 0, stream,
                       dates, out, h0seq, h1seq, cnt, act_i, jmap, S_ptr);
    hipLaunchKernelGGL(chain_kernel, dim3(2 * GA), dim3(512), 0, stream,
                       x, Wih0, Whh0, bih0, bhh0, Wih1, Whh1, bih1, bhh1,
                       h0seq, h1seq, cntA, cntB, act_i, S_ptr);
    hipLaunchKernelGGL(finalize_kernel, dim3(NB), dim3(256), 0, stream,
                       h1seq, jmap, out);
}

// Round 2
// 11856.469 us; speedup vs baseline: 4.0281x; 4.0281x over previous
//
#include <hip/hip_runtime.h>
#include <hip/hip_bf16.h>

// Problem dims (fixed by reference): N=256, T=32, F=H=512, L=2
#define HD 512
#define TT 32
#define NB 256
#define SEQROWS 8193          // 1 zero row + up to 8192 chain steps
#define MAXS 8192
#define GA 32                 // workgroups per role (A=layer0, B=layer1)

__device__ __forceinline__ float fast_sigmoid(float x) {
    return 1.0f / (1.0f + __expf(-x));
}
__device__ __forceinline__ float fast_tanh(float x) {
    return 1.0f - 2.0f / (__expf(2.0f * x) + 1.0f);
}

// ---------------------------------------------------------------------------
// init: block 0 -> scan dates, build active list / output map, zero h rows,
//       write dates to out; blocks 1..256 -> zero the step flags (2*256K ints)
// ---------------------------------------------------------------------------
__global__ __launch_bounds__(256) void init_kernel(
    const int* __restrict__ dates, float* __restrict__ out,
    float* __restrict__ h0seq, float* __restrict__ h1seq,
    int* __restrict__ flags, int* __restrict__ act_idx,
    int* __restrict__ jmap, int* __restrict__ S_ptr)
{
    const int b = blockIdx.x, tid = threadIdx.x;
    if (b == 0) {
        __shared__ int sc[NB];
        int d = dates[tid];
        int active = (tid == 0) ? 1 : (d != dates[tid - 1] ? 1 : 0);
        sc[tid] = active;
        for (int off = 1; off < NB; off <<= 1) {
            __syncthreads();
            int v = sc[tid] + ((tid >= off) ? sc[tid - off] : 0);
            __syncthreads();
            sc[tid] = v;
        }
        __syncthreads();
        int incl = sc[tid];               // inclusive count of actives in [0..tid]
        jmap[tid] = incl - 1;             // which active element's output this copies
        if (active) act_idx[incl - 1] = tid;
        if (tid == NB - 1) *S_ptr = incl * TT;
        out[tid] = (float)d;              // output 0: dates passthrough
        for (int i = tid; i < HD; i += 256) { h0seq[i] = 0.f; h1seq[i] = 0.f; }
    } else {
        // zero flagsA (MAXS*32) + flagsB (MAXS*32) = 524288 ints, 2048 per block
        int base = (b - 1) * 2048;
#pragma unroll
        for (int i = 0; i < 8; i++) flags[base + i * 256 + tid] = 0;
    }
}

// ---------------------------------------------------------------------------
// chain: 64 persistent WGs, NO fences. WGs 0..31 = layer0 (input x), WGs
// 32..63 = layer1 (input = layer0's published h0). All cross-WG data moves
// via relaxed agent-scope atomics (single sc0sc1 load/store instructions that
// bypass L1/L2 -> LLC), avoiding the L2 writeback/invalidate that an agent
// fence implies on multi-XCD gfx950 (R1: ~12us/step => fences dominated).
//
// Thread (hl = tid>>5, c = tid&31) owns output row hi = g*16+hl and columns
// {c + 32j}, j=0..15 (stride-32 => conflict-free LDS reads, coalesced weight
// loads). 96 fp32 weights register-resident per thread.
// ---------------------------------------------------------------------------
__global__ __launch_bounds__(512) void chain_kernel(
    const float* __restrict__ x,
    const float* __restrict__ Wih0, const float* __restrict__ Whh0,
    const float* __restrict__ bih0, const float* __restrict__ bhh0,
    const float* __restrict__ Wih1, const float* __restrict__ Whh1,
    const float* __restrict__ bih1, const float* __restrict__ bhh1,
    float* h0seq, float* h1seq,
    int* flagsA, int* flagsB,
    const int* __restrict__ act_idx, const int* __restrict__ S_ptr)
{
    const int wg   = blockIdx.x;
    const bool roleB = (wg >= GA);
    const int g    = roleB ? wg - GA : wg;     // 0..31
    const int tid  = threadIdx.x;
    const int hl   = tid >> 5;                 // 0..15: local h row
    const int c    = tid & 31;                 // 0..31: column lane
    const int hi   = g * 16 + hl;              // 0..511: owned h output

    __shared__ float hbuf[HD];                 // own h(s-1) row
    __shared__ float xbuf[HD];                 // role B: h0(s) row

    const float* Wi = roleB ? Wih1 : Wih0;
    const float* Wh = roleB ? Whh1 : Whh0;
    const float* bi = roleB ? bih1 : bih0;
    const float* bh = roleB ? bhh1 : bhh0;

    // ---- register-resident weights: column pattern c + 32j ----
    float wir[16], wiz[16], win[16], whr[16], whz[16], whn[16];
    {
        const size_t GS = (size_t)HD * HD;
        const float* rI = Wi + (size_t)hi * HD + c;
        const float* rH = Wh + (size_t)hi * HD + c;
#pragma unroll
        for (int j = 0; j < 16; j++) {
            wir[j] = rI[32 * j];
            wiz[j] = rI[GS + 32 * j];
            win[j] = rI[2 * GS + 32 * j];
            whr[j] = rH[32 * j];
            whz[j] = rH[GS + 32 * j];
            whn[j] = rH[2 * GS + 32 * j];
        }
    }
    const float br   = bi[hi] + bh[hi];
    const float bz   = bi[HD + hi] + bh[HD + hi];
    const float bin_ = bi[2 * HD + hi];
    const float bhn_ = bh[2 * HD + hi];

    const int S = *S_ptr;
    float* outseq = roleB ? h1seq : h0seq;
    int*   myflags = roleB ? flagsB : flagsA;
    float hown = 0.0f;   // leader lanes (c==0) carry their own h across steps

    for (int s = 0; s < S; s++) {
        // ---- role A: prefetch x slice before the spin (independent data) ----
        float xr[16];
        if (!roleB) {
            int n = act_idx[s >> 5];
            const float* invec = x + ((size_t)n * TT + (s & 31)) * HD + c;
#pragma unroll
            for (int j = 0; j < 16; j++) xr[j] = invec[32 * j];
        }

        // ---- wave 0 polls producer flags (per-WG slots, no contention) ----
        if (tid < 64) {
            int* p = nullptr;
            if (!roleB) {
                if (s > 0) p = flagsA + (size_t)(s - 1) * GA + c;   // both half-waves
            } else {
                if (tid < 32)      p = flagsA + (size_t)s * GA + c; // h0 after step s
                else if (s > 0)    p = flagsB + (size_t)(s - 1) * GA + c;
            }
            bool done = (p == nullptr);
            int it = 0;
            while (!__all(done)) {
                if (!done)
                    done = __hip_atomic_load(p, __ATOMIC_RELAXED,
                                             __HIP_MEMORY_SCOPE_AGENT) != 0;
                if (!done) __builtin_amdgcn_s_sleep(1);
                if (++it > 50000000) break;    // fail loudly, don't hang
            }
        }
        __syncthreads();

        // ---- stage coherent rows into LDS: 1 lane-coalesced 4B load each ----
        hbuf[tid] = __hip_atomic_load(outseq + (size_t)s * HD + tid,
                                      __ATOMIC_RELAXED, __HIP_MEMORY_SCOPE_AGENT);
        if (roleB)
            xbuf[tid] = __hip_atomic_load(h0seq + (size_t)(s + 1) * HD + tid,
                                          __ATOMIC_RELAXED, __HIP_MEMORY_SCOPE_AGENT);
        __syncthreads();

        // ---- matvec partials over this lane's 16 columns ----
        float pr = 0.f, pz = 0.f, pin = 0.f, phn = 0.f;
#pragma unroll
        for (int j = 0; j < 16; j++) {
            float hv = hbuf[c + 32 * j];
            float xv = roleB ? xbuf[c + 32 * j] : xr[j];
            pr  = fmaf(wir[j], xv, pr);
            pz  = fmaf(wiz[j], xv, pz);
            pin = fmaf(win[j], xv, pin);
            pr  = fmaf(whr[j], hv, pr);
            pz  = fmaf(whz[j], hv, pz);
            phn = fmaf(whn[j], hv, phn);
        }
        // ---- reduce across the 32 column lanes (in-wave) ----
#pragma unroll
        for (int m = 1; m < 32; m <<= 1) {
            pr  += __shfl_xor(pr,  m, 64);
            pz  += __shfl_xor(pz,  m, 64);
            pin += __shfl_xor(pin, m, 64);
            phn += __shfl_xor(phn, m, 64);
        }
        if (c == 0) {
            float r  = fast_sigmoid(pr + br);
            float z  = fast_sigmoid(pz + bz);
            float nn = fast_tanh(pin + bin_ + r * (phn + bhn_));
            hown = (1.0f - z) * nn + z * hown;
            __hip_atomic_store(outseq + (size_t)(s + 1) * HD + hi, hown,
                               __ATOMIC_RELAXED, __HIP_MEMORY_SCOPE_AGENT);
            __builtin_amdgcn_s_waitcnt(0);   // store ACKed at LLC before barrier
        }
        __syncthreads();                      // all 16 leader stores globally visible
        if (tid == 0) {
            __hip_atomic_store(myflags + (size_t)s * GA + g, 1,
                               __ATOMIC_RELAXED, __HIP_MEMORY_SCOPE_AGENT);
        }
    }
}

// ---------------------------------------------------------------------------
// finalize: states[n] = h1 after last step of active element jmap[n]
// ---------------------------------------------------------------------------
__global__ __launch_bounds__(256) void finalize_kernel(
    const float* __restrict__ h1seq, const int* __restrict__ jmap,
    float* __restrict__ out)
{
    const int n = blockIdx.x;
    const int j = jmap[n];
    const float* src = h1seq + ((size_t)j * TT + TT) * HD;   // row (j+1)*32
    float* dst = out + NB + (size_t)n * HD;
    for (int i = threadIdx.x; i < HD; i += 256) dst[i] = src[i];
}

extern "C" void kernel_launch(void* const* d_in, const int* in_sizes, int n_in,
                              void* d_out, int out_size, void* d_ws, size_t ws_size,
                              hipStream_t stream)
{
    const int*   dates = (const int*)d_in[0];
    const float* x     = (const float*)d_in[1];
    const float* Wih0  = (const float*)d_in[2];
    const float* Whh0  = (const float*)d_in[3];
    const float* bih0  = (const float*)d_in[4];
    const float* bhh0  = (const float*)d_in[5];
    const float* Wih1  = (const float*)d_in[6];
    const float* Whh1  = (const float*)d_in[7];
    const float* bih1  = (const float*)d_in[8];
    const float* bhh1  = (const float*)d_in[9];
    float* out = (float*)d_out;

    // workspace layout (~35.7 MB)
    float* h0seq  = (float*)d_ws;                       // 8193*512
    float* h1seq  = h0seq + (size_t)SEQROWS * HD;       // 8193*512
    int*   flags  = (int*)(h1seq + (size_t)SEQROWS * HD);
    int*   flagsA = flags;                              // 8192*32
    int*   flagsB = flags + (size_t)MAXS * GA;          // 8192*32
    int*   act_i  = flagsB + (size_t)MAXS * GA;         // 256
    int*   jmap   = act_i + NB;                         // 256
    int*   S_ptr  = jmap + NB;                          // 1

    hipLaunchKernelGGL(init_kernel, dim3(257), dim3(256), 0, stream,
                       dates, out, h0seq, h1seq, flags, act_i, jmap, S_ptr);
    hipLaunchKernelGGL(chain_kernel, dim3(2 * GA), dim3(512), 0, stream,
                       x, Wih0, Whh0, bih0, bhh0, Wih1, Whh1, bih1, bhh1,
                       h0seq, h1seq, flagsA, flagsB, act_i, S_ptr);
    hipLaunchKernelGGL(finalize_kernel, dim3(NB), dim3(256), 0, stream,
                       h1seq, jmap, out);
}

// Round 3
// 10566.338 us; speedup vs baseline: 4.5200x; 1.1221x over previous
//
#include <hip/hip_runtime.h>
#include <hip/hip_bf16.h>

// Problem dims (fixed by reference): N=256, T=32, F=H=512, L=2
#define HD 512
#define TT 32
#define NB 256
#define SEQROWS 8193          // 1 zero row + up to 8192 chain steps
#define GA 32                 // workgroups per role (A=layer0, B=layer1)
#define SENT_U 0x7FC0ABCDu    // quiet-NaN sentinel: unreachable by GRU math

typedef float vf16 __attribute__((ext_vector_type(16)));

__device__ __forceinline__ float fast_sigmoid(float x) {
    return 1.0f / (1.0f + __expf(-x));
}
__device__ __forceinline__ float fast_tanh(float x) {
    return 1.0f - 2.0f / (__expf(2.0f * x) + 1.0f);
}

__device__ __forceinline__ float coh_load(const float* p) {
    return __hip_atomic_load(p, __ATOMIC_RELAXED, __HIP_MEMORY_SCOPE_AGENT);
}
__device__ __forceinline__ void coh_store(float* p, float v) {
    __hip_atomic_store(p, v, __ATOMIC_RELAXED, __HIP_MEMORY_SCOPE_AGENT);
}

// ---------------------------------------------------------------------------
// init: block 0 -> dates scan, active list, jmap, S, zero h row 0, out dates;
//       blocks 1..1024 -> sentinel-fill rows 1..8192 of both h sequences
//       (exactly 2*8192*512 words = 2,097,152 uint4; 8 uint4 per thread).
// ---------------------------------------------------------------------------
__global__ __launch_bounds__(256) void init_kernel(
    const int* __restrict__ dates, float* __restrict__ out,
    float* __restrict__ h0seq, float* __restrict__ h1seq,
    int* __restrict__ act_idx, int* __restrict__ jmap, int* __restrict__ S_ptr)
{
    const int b = blockIdx.x, tid = threadIdx.x;
    if (b == 0) {
        __shared__ int sc[NB];
        int d = dates[tid];
        int active = (tid == 0) ? 1 : (d != dates[tid - 1] ? 1 : 0);
        sc[tid] = active;
        for (int off = 1; off < NB; off <<= 1) {
            __syncthreads();
            int v = sc[tid] + ((tid >= off) ? sc[tid - off] : 0);
            __syncthreads();
            sc[tid] = v;
        }
        __syncthreads();
        int incl = sc[tid];               // inclusive actives in [0..tid]
        jmap[tid] = incl - 1;
        if (active) act_idx[incl - 1] = tid;
        if (tid == NB - 1) *S_ptr = incl * TT;
        out[tid] = (float)d;              // output 0: dates passthrough
        for (int i = tid; i < HD; i += 256) { h0seq[i] = 0.f; h1seq[i] = 0.f; }
    } else {
        const uint4 sv = make_uint4(SENT_U, SENT_U, SENT_U, SENT_U);
        const size_t HALF = (size_t)(SEQROWS - 1) * HD / 4;   // uint4 per buffer
        size_t base = (size_t)(b - 1) * 2048 + tid;
#pragma unroll
        for (int k = 0; k < 8; k++) {
            size_t i = base + (size_t)k * 256;                // uint4 index
            uint4* dst = (i < HALF)
                ? reinterpret_cast<uint4*>(h0seq + HD) + i
                : reinterpret_cast<uint4*>(h1seq + HD) + (i - HALF);
            *dst = sv;
        }
    }
}

// ---------------------------------------------------------------------------
// chain: 64 persistent WGs, sentinel-poll handoff (no flags, no fences).
// WGs 0..31 = layer0 (input x), WGs 32..63 = layer1 (input = h0 stream).
// Thread (hl=tid>>5, c=tid&31) owns h row hi=g*16+hl, columns {c+32j}.
// 96 weights/thread held in 6 x ext_vector_type(16) (forced VGPR residency;
// R2's float[16] arrays were demoted: VGPR_Count=88 < 96 weights).
// ---------------------------------------------------------------------------
__global__ __launch_bounds__(512, 2) void chain_kernel(
    const float* __restrict__ x,
    const float* __restrict__ Wih0, const float* __restrict__ Whh0,
    const float* __restrict__ bih0, const float* __restrict__ bhh0,
    const float* __restrict__ Wih1, const float* __restrict__ Whh1,
    const float* __restrict__ bih1, const float* __restrict__ bhh1,
    float* h0seq, float* h1seq,
    const int* __restrict__ act_idx, const int* __restrict__ S_ptr)
{
    const int wg   = blockIdx.x;
    const bool roleB = (wg >= GA);
    const int g    = roleB ? wg - GA : wg;     // 0..31
    const int tid  = threadIdx.x;
    const int hl   = tid >> 5;                 // 0..15: local h row
    const int c    = tid & 31;                 // 0..31: column lane
    const int hi   = g * 16 + hl;              // owned h output index

    __shared__ float hbufs[2][HD];             // own h(s-1) row, double-buffered
    __shared__ float xbufs[2][HD];             // role B: h0(s) row

    const float* Wi = roleB ? Wih1 : Wih0;
    const float* Wh = roleB ? Whh1 : Whh0;
    const float* bi = roleB ? bih1 : bih0;
    const float* bh = roleB ? bhh1 : bhh0;

    vf16 wir, wiz, win, whr, whz, whn;
    {
        const size_t GS = (size_t)HD * HD;
        const float* rI = Wi + (size_t)hi * HD + c;
        const float* rH = Wh + (size_t)hi * HD + c;
#pragma unroll
        for (int j = 0; j < 16; j++) {
            wir[j] = rI[32 * j];
            wiz[j] = rI[GS + 32 * j];
            win[j] = rI[2 * GS + 32 * j];
            whr[j] = rH[32 * j];
            whz[j] = rH[GS + 32 * j];
            whn[j] = rH[2 * GS + 32 * j];
        }
    }
    const float br   = bi[hi] + bh[hi];
    const float bz   = bi[HD + hi] + bh[HD + hi];
    const float bin_ = bi[2 * HD + hi];
    const float bhn_ = bh[2 * HD + hi];

    const int S = *S_ptr;
    float* outseq = roleB ? h1seq : h0seq;
    float hown = 0.0f;                         // leader lanes carry their h

    for (int s = 0; s < S; s++) {
        const int buf = s & 1;

        // ---- role A: x slice + x-partials BEFORE the wait (independent) ----
        float pr = 0.f, pz = 0.f, pin = 0.f;
        if (!roleB) {
            int n = act_idx[s >> 5];
            const float* xp = x + ((size_t)n * TT + (s & 31)) * HD + c;
            float xr[16];
#pragma unroll
            for (int j = 0; j < 16; j++) xr[j] = xp[32 * j];
#pragma unroll
            for (int j = 0; j < 16; j++) {
                pr  = fmaf(wir[j], xr[j], pr);
                pz  = fmaf(wiz[j], xr[j], pz);
                pin = fmaf(win[j], xr[j], pin);
            }
        }

        // ---- sentinel-poll the input rows: 1 coalesced word per thread ----
        const float* hp = outseq + (size_t)s * HD + tid;
        float hv = coh_load(hp);
        if (!roleB) {
            int it = 0;
            while (__float_as_uint(hv) == SENT_U) {
                hv = coh_load(hp);
                if (++it > 20000000) break;    // fail loudly, don't hang
            }
            hbufs[buf][tid] = hv;
        } else {
            const float* xp2 = h0seq + (size_t)(s + 1) * HD + tid;
            float xv = coh_load(xp2);
            int it = 0;
            while (__float_as_uint(hv) == SENT_U || __float_as_uint(xv) == SENT_U) {
                if (__float_as_uint(hv) == SENT_U) hv = coh_load(hp);
                if (__float_as_uint(xv) == SENT_U) xv = coh_load(xp2);
                if (++it > 20000000) break;
            }
            hbufs[buf][tid] = hv;
            xbufs[buf][tid] = xv;
        }
        __syncthreads();   // only barrier per step (double-buffered LDS)

        // ---- post-detect matvec ----
        float phn = 0.f;
#pragma unroll
        for (int j = 0; j < 16; j++) {
            float h2 = hbufs[buf][c + 32 * j];
            pr  = fmaf(whr[j], h2, pr);
            pz  = fmaf(whz[j], h2, pz);
            phn = fmaf(whn[j], h2, phn);
        }
        if (roleB) {
#pragma unroll
            for (int j = 0; j < 16; j++) {
                float x2 = xbufs[buf][c + 32 * j];
                pr  = fmaf(wir[j], x2, pr);
                pz  = fmaf(wiz[j], x2, pz);
                pin = fmaf(win[j], x2, pin);
            }
        }
#pragma unroll
        for (int m = 1; m < 32; m <<= 1) {
            pr  += __shfl_xor(pr,  m, 64);
            pz  += __shfl_xor(pz,  m, 64);
            pin += __shfl_xor(pin, m, 64);
            phn += __shfl_xor(phn, m, 64);
        }
        if (c == 0) {
            float r  = fast_sigmoid(pr + br);
            float z  = fast_sigmoid(pz + bz);
            float nn = fast_tanh(pin + bin_ + r * (phn + bhn_));
            hown = (1.0f - z) * nn + z * hown;
            coh_store(outseq + (size_t)(s + 1) * HD + hi, hown);
        }
    }
}

// ---------------------------------------------------------------------------
// finalize: states[n] = h1 after last step of active element jmap[n].
// Agent-scope loads: chain's sc1 stores bypassed per-XCD L2, and init's
// sentinel writes may sit stale in this XCD's L2.
// ---------------------------------------------------------------------------
__global__ __launch_bounds__(256) void finalize_kernel(
    const float* __restrict__ h1seq, const int* __restrict__ jmap,
    float* __restrict__ out)
{
    const int n = blockIdx.x;
    const int j = jmap[n];
    const float* src = h1seq + ((size_t)j * TT + TT) * HD;   // row (j+1)*32
    float* dst = out + NB + (size_t)n * HD;
    for (int i = threadIdx.x; i < HD; i += 256)
        dst[i] = coh_load(src + i);
}

extern "C" void kernel_launch(void* const* d_in, const int* in_sizes, int n_in,
                              void* d_out, int out_size, void* d_ws, size_t ws_size,
                              hipStream_t stream)
{
    const int*   dates = (const int*)d_in[0];
    const float* x     = (const float*)d_in[1];
    const float* Wih0  = (const float*)d_in[2];
    const float* Whh0  = (const float*)d_in[3];
    const float* bih0  = (const float*)d_in[4];
    const float* bhh0  = (const float*)d_in[5];
    const float* Wih1  = (const float*)d_in[6];
    const float* Whh1  = (const float*)d_in[7];
    const float* bih1  = (const float*)d_in[8];
    const float* bhh1  = (const float*)d_in[9];
    float* out = (float*)d_out;

    // workspace layout (~33.6 MB)
    float* h0seq  = (float*)d_ws;                       // 8193*512
    float* h1seq  = h0seq + (size_t)SEQROWS * HD;       // 8193*512
    int*   act_i  = (int*)(h1seq + (size_t)SEQROWS * HD);
    int*   jmap   = act_i + NB;                         // 256
    int*   S_ptr  = jmap + NB;                          // 1

    hipLaunchKernelGGL(init_kernel, dim3(1025), dim3(256), 0, stream,
                       dates, out, h0seq, h1seq, act_i, jmap, S_ptr);
    hipLaunchKernelGGL(chain_kernel, dim3(2 * GA), dim3(512), 0, stream,
                       x, Wih0, Whh0, bih0, bhh0, Wih1, Whh1, bih1, bhh1,
                       h0seq, h1seq, act_i, S_ptr);
    hipLaunchKernelGGL(finalize_kernel, dim3(NB), dim3(256), 0, stream,
                       h1seq, jmap, out);
}